// Round 1
// baseline (160.250 us; speedup 1.0000x reference)
//
#include <hip/hip_runtime.h>

#define SEQ   2048
#define BATCH 64
#define ENC_HID 1024
#define DEC_HID 1024
#define ATT_D 512

// ---------------------------------------------------------------------------
// fast tanh: tanh(x) = 1 - 2/(1 + exp(2x)) = 1 - 2*rcp(1 + exp2(x*2*log2(e)))
// saturates correctly for large |x| (exp2->inf -> 1 ; exp2->0 -> -1)
__device__ __forceinline__ float fast_tanh(float x) {
    float e = __builtin_amdgcn_exp2f(x * 2.8853900817779268f);
    return 1.0f - 2.0f * __builtin_amdgcn_rcpf(1.0f + e);
}

// ---------------------------------------------------------------------------
// Kernel 1: dec_att[b][a] = sum_k dec_out[b][k] * W_dec[a][k]
// one wave per output element; K=1024 -> 4 float4 per lane
__global__ __launch_bounds__(256) void k_dec_att(const float* __restrict__ dec_out,
                                                 const float* __restrict__ W_dec,
                                                 float* __restrict__ dec_att) {
    int w    = blockIdx.x * 4 + (threadIdx.x >> 6);
    int lane = threadIdx.x & 63;
    int b = w >> 9;          // / ATT_D
    int a = w & (ATT_D - 1);
    const float4* wd = (const float4*)(W_dec + (size_t)a * DEC_HID);
    const float4* dd = (const float4*)(dec_out + (size_t)b * DEC_HID);
    float acc = 0.f;
#pragma unroll
    for (int j = 0; j < 4; ++j) {
        int idx = j * 64 + lane;
        float4 x = wd[idx];
        float4 y = dd[idx];
        acc += x.x * y.x + x.y * y.y + x.z * y.z + x.w * y.w;
    }
#pragma unroll
    for (int off = 32; off; off >>= 1) acc += __shfl_xor(acc, off, 64);
    if (lane == 0) dec_att[(size_t)b * ATT_D + a] = acc;
}

// ---------------------------------------------------------------------------
// Kernel 2: scores[b][s] = sum_a tanh(enc_att[s][b][a] + dec_att[b][a]) * att_v[a]
// one wave per (s,b); ATT_D=512 -> 2 float4 per lane
__global__ __launch_bounds__(256) void k_scores(const float* __restrict__ enc_att,
                                                const float* __restrict__ dec_att,
                                                const float* __restrict__ att_v,
                                                float* __restrict__ scores) {
    int w    = blockIdx.x * 4 + (threadIdx.x >> 6);
    int lane = threadIdx.x & 63;
    int b = w & (BATCH - 1);
    int s = w >> 6;
    const float4* ea = (const float4*)(enc_att + ((size_t)s * BATCH + b) * ATT_D);
    const float4* da = (const float4*)(dec_att + (size_t)b * ATT_D);
    const float4* av = (const float4*)att_v;
    float acc = 0.f;
#pragma unroll
    for (int j = 0; j < 2; ++j) {
        int idx = j * 64 + lane;
        float4 e = ea[idx];
        float4 d = da[idx];
        float4 v = av[idx];
        acc += fast_tanh(e.x + d.x) * v.x;
        acc += fast_tanh(e.y + d.y) * v.y;
        acc += fast_tanh(e.z + d.z) * v.z;
        acc += fast_tanh(e.w + d.w) * v.w;
    }
#pragma unroll
    for (int off = 32; off; off >>= 1) acc += __shfl_xor(acc, off, 64);
    if (lane == 0) scores[(size_t)b * SEQ + s] = acc;
}

// ---------------------------------------------------------------------------
// Kernel 3: in-place row softmax. one block (256 thr) per batch row of 2048.
__global__ __launch_bounds__(256) void k_softmax(float* __restrict__ scores) {
    __shared__ float red[8];
    int b = blockIdx.x;
    int t = threadIdx.x;
    int lane = t & 63, wv = t >> 6;
    float4* row = (float4*)(scores + (size_t)b * SEQ);
    float4 x0 = row[t];
    float4 x1 = row[t + 256];
    float mx = fmaxf(fmaxf(fmaxf(x0.x, x0.y), fmaxf(x0.z, x0.w)),
                     fmaxf(fmaxf(x1.x, x1.y), fmaxf(x1.z, x1.w)));
#pragma unroll
    for (int off = 32; off; off >>= 1) mx = fmaxf(mx, __shfl_xor(mx, off, 64));
    if (lane == 0) red[wv] = mx;
    __syncthreads();
    mx = fmaxf(fmaxf(red[0], red[1]), fmaxf(red[2], red[3]));

    const float L2E = 1.4426950408889634f;
    float4 e0, e1;
    e0.x = __builtin_amdgcn_exp2f((x0.x - mx) * L2E);
    e0.y = __builtin_amdgcn_exp2f((x0.y - mx) * L2E);
    e0.z = __builtin_amdgcn_exp2f((x0.z - mx) * L2E);
    e0.w = __builtin_amdgcn_exp2f((x0.w - mx) * L2E);
    e1.x = __builtin_amdgcn_exp2f((x1.x - mx) * L2E);
    e1.y = __builtin_amdgcn_exp2f((x1.y - mx) * L2E);
    e1.z = __builtin_amdgcn_exp2f((x1.z - mx) * L2E);
    e1.w = __builtin_amdgcn_exp2f((x1.w - mx) * L2E);
    float sum = e0.x + e0.y + e0.z + e0.w + e1.x + e1.y + e1.z + e1.w;
#pragma unroll
    for (int off = 32; off; off >>= 1) sum += __shfl_xor(sum, off, 64);
    if (lane == 0) red[4 + wv] = sum;
    __syncthreads();
    sum = red[4] + red[5] + red[6] + red[7];
    float inv = 1.0f / sum;
    e0.x *= inv; e0.y *= inv; e0.z *= inv; e0.w *= inv;
    e1.x *= inv; e1.y *= inv; e1.z *= inv; e1.w *= inv;
    row[t]       = e0;
    row[t + 256] = e1;
}

// ---------------------------------------------------------------------------
// Kernel 4a: partial context. block = (b, s-chunk of 64). 256 thr * float4 = 1024 h.
__global__ __launch_bounds__(256) void k_context_partial(const float* __restrict__ enc_outs,
                                                         const float* __restrict__ weights,
                                                         float* __restrict__ partial) {
    __shared__ float wl[64];
    int b     = blockIdx.x >> 5;
    int chunk = blockIdx.x & 31;
    int s0    = chunk * 64;
    int t     = threadIdx.x;
    if (t < 64) wl[t] = weights[(size_t)b * SEQ + s0 + t];
    __syncthreads();
    const float4* base = (const float4*)enc_outs;
    float4 acc = {0.f, 0.f, 0.f, 0.f};
#pragma unroll 4
    for (int i = 0; i < 64; ++i) {
        int s = s0 + i;
        size_t idx = ((size_t)s * BATCH + b) * (ENC_HID / 4) + t;
        float4 e = base[idx];
        float w = wl[i];
        acc.x += w * e.x; acc.y += w * e.y; acc.z += w * e.z; acc.w += w * e.w;
    }
    ((float4*)(partial + (size_t)blockIdx.x * ENC_HID))[t] = acc;
}

// Kernel 4b: reduce 32 partials per (b,h)
__global__ __launch_bounds__(256) void k_context_reduce(const float* __restrict__ partial,
                                                        float* __restrict__ context) {
    int b = blockIdx.x;
    int t = threadIdx.x;
    float4 acc = {0.f, 0.f, 0.f, 0.f};
#pragma unroll 8
    for (int c = 0; c < 32; ++c) {
        float4 e = ((const float4*)(partial + ((size_t)b * 32 + c) * ENC_HID))[t];
        acc.x += e.x; acc.y += e.y; acc.z += e.z; acc.w += e.w;
    }
    ((float4*)(context + (size_t)b * ENC_HID))[t] = acc;
}

// ---- fallback path (small ws): zero + atomic accumulate -------------------
__global__ __launch_bounds__(256) void k_zero(float* __restrict__ context) {
    int b = blockIdx.x, t = threadIdx.x;
    float4 z = {0.f, 0.f, 0.f, 0.f};
    ((float4*)(context + (size_t)b * ENC_HID))[t] = z;
}

__global__ __launch_bounds__(256) void k_context_atomic(const float* __restrict__ enc_outs,
                                                        const float* __restrict__ weights,
                                                        float* __restrict__ context) {
    __shared__ float wl[64];
    int b     = blockIdx.x >> 5;
    int chunk = blockIdx.x & 31;
    int s0    = chunk * 64;
    int t     = threadIdx.x;
    if (t < 64) wl[t] = weights[(size_t)b * SEQ + s0 + t];
    __syncthreads();
    const float4* base = (const float4*)enc_outs;
    float4 acc = {0.f, 0.f, 0.f, 0.f};
#pragma unroll 4
    for (int i = 0; i < 64; ++i) {
        int s = s0 + i;
        size_t idx = ((size_t)s * BATCH + b) * (ENC_HID / 4) + t;
        float4 e = base[idx];
        float w = wl[i];
        acc.x += w * e.x; acc.y += w * e.y; acc.z += w * e.z; acc.w += w * e.w;
    }
    float* dst = context + (size_t)b * ENC_HID + t * 4;
    atomicAdd(dst + 0, acc.x);
    atomicAdd(dst + 1, acc.y);
    atomicAdd(dst + 2, acc.z);
    atomicAdd(dst + 3, acc.w);
}

// ---------------------------------------------------------------------------
extern "C" void kernel_launch(void* const* d_in, const int* in_sizes, int n_in,
                              void* d_out, int out_size, void* d_ws, size_t ws_size,
                              hipStream_t stream) {
    const float* dec_out  = (const float*)d_in[0];   // (B, DEC_HID)
    const float* enc_outs = (const float*)d_in[1];   // (SEQ, B, ENC_HID)
    const float* enc_att  = (const float*)d_in[2];   // (SEQ, B, ATT_D)
    const float* W_dec    = (const float*)d_in[3];   // (ATT_D, DEC_HID)
    const float* att_v    = (const float*)d_in[4];   // (ATT_D,)

    float* out     = (float*)d_out;
    float* context = out;                          // B*ENC_HID floats
    float* weights = out + BATCH * ENC_HID;        // B*SEQ floats (scores in-place)

    float* dec_att = (float*)d_ws;                 // B*ATT_D floats
    float* partial = (float*)d_ws + BATCH * ATT_D; // 2048*ENC_HID floats

    // 1. dec_att = dec_out @ W_dec^T  (one wave per output)
    k_dec_att<<<(BATCH * ATT_D) / 4, 256, 0, stream>>>(dec_out, W_dec, dec_att);

    // 2. scores (written into the weights slot of d_out)
    k_scores<<<(SEQ * BATCH) / 4, 256, 0, stream>>>(enc_att, dec_att, att_v, weights);

    // 3. softmax in-place -> weights
    k_softmax<<<BATCH, 256, 0, stream>>>(weights);

    // 4. context
    size_t need = ((size_t)BATCH * ATT_D + (size_t)2048 * ENC_HID) * sizeof(float);
    if (ws_size >= need) {
        k_context_partial<<<2048, 256, 0, stream>>>(enc_outs, weights, partial);
        k_context_reduce<<<BATCH, 256, 0, stream>>>(partial, context);
    } else {
        k_zero<<<BATCH, 256, 0, stream>>>(context);
        k_context_atomic<<<2048, 256, 0, stream>>>(enc_outs, weights, context);
    }
}